// Round 1
// baseline (271.046 us; speedup 1.0000x reference)
//
#include <hip/hip_runtime.h>

#define ITEMS_PER_BLOCK 10
#define NTHREADS 256
#define NQ 25
#define KVD 9
#define WPAD 12   // padded weight row (floats) -> 48 B, 16B aligned
#define KVROW 24  // k at [0..9), v at [12..21), per token row (96 B)

__device__ __forceinline__ float dot9(const float* __restrict__ w,
                                      const float* __restrict__ xv) {
  float4 a = *(const float4*)(w);
  float4 b = *(const float4*)(w + 4);
  float c = w[8];
  return fmaf(a.x, xv[0], fmaf(a.y, xv[1], fmaf(a.z, xv[2], fmaf(a.w, xv[3],
         fmaf(b.x, xv[4], fmaf(b.y, xv[5], fmaf(b.z, xv[6], fmaf(b.w, xv[7],
         c * xv[8]))))))));
}

__global__ __launch_bounds__(NTHREADS) void attn_fused(
    const float* __restrict__ x, const float* __restrict__ mask,
    const float* __restrict__ Wq, const float* __restrict__ bq,
    const float* __restrict__ Wk, const float* __restrict__ bk,
    const float* __restrict__ Wv, const float* __restrict__ bv,
    const float* __restrict__ gamma, const float* __restrict__ beta,
    float* __restrict__ out, int B) {
  __shared__ __align__(16) float sW[3][4][KVD][WPAD];  // [q/k/v][group][row e][d]
  __shared__ __align__(16) float sB[3][4][KVD];
  __shared__ __align__(16) float sMask[NQ];
  __shared__ __align__(16) float sG[KVD];
  __shared__ __align__(16) float sBeta[KVD];
  __shared__ __align__(16) float sKV[ITEMS_PER_BLOCK][NQ][KVROW];

  const int tid = threadIdx.x;

  // ---- stage parameters into LDS ----
  for (int i = tid; i < 324; i += NTHREADS) {  // 4*9*9 per matrix
    int g = i / 81;
    int r = (i - g * 81) / 9;
    int d = i - g * 81 - r * 9;
    sW[0][g][r][d] = Wq[i];
    sW[1][g][r][d] = Wk[i];
    sW[2][g][r][d] = Wv[i];
  }
  for (int i = tid; i < 36; i += NTHREADS) {
    int g = i / 9, d = i - g * 9;
    sB[0][g][d] = bq[i];
    sB[1][g][d] = bk[i];
    sB[2][g][d] = bv[i];
  }
  if (tid < NQ) sMask[tid] = mask[tid] * -1e9f;
  if (tid < KVD) { sG[tid] = gamma[tid]; sBeta[tid] = beta[tid]; }
  __syncthreads();

  const int il = tid / NQ;
  const int tk = tid - il * NQ;
  const long item = (long)blockIdx.x * ITEMS_PER_BLOCK + il;
  const bool active = (tid < ITEMS_PER_BLOCK * NQ) && (item < (long)B);

  float xv[KVD], q[KVD];
  if (active) {
    const float* xp = x + item * 225 + tk * KVD;
#pragma unroll
    for (int d = 0; d < KVD; ++d) xv[d] = xp[d];

    const int g = (tk < 3) ? 0 : (tk < 13) ? 1 : (tk < 23) ? 2 : 3;
    const float* wq = &sW[0][g][0][0];
    const float* wk = &sW[1][g][0][0];
    const float* wv = &sW[2][g][0][0];

    float kr[KVD], vr[KVD];
#pragma unroll
    for (int e = 0; e < KVD; ++e) {
      q[e]  = sB[0][g][e] + dot9(wq + e * WPAD, xv);
      kr[e] = sB[1][g][e] + dot9(wk + e * WPAD, xv);
      vr[e] = sB[2][g][e] + dot9(wv + e * WPAD, xv);
    }
    float* kvp = &sKV[il][tk][0];
    *(float4*)(kvp)      = make_float4(kr[0], kr[1], kr[2], kr[3]);
    *(float4*)(kvp + 4)  = make_float4(kr[4], kr[5], kr[6], kr[7]);
    kvp[8] = kr[8];
    *(float4*)(kvp + 12) = make_float4(vr[0], vr[1], vr[2], vr[3]);
    *(float4*)(kvp + 16) = make_float4(vr[4], vr[5], vr[6], vr[7]);
    kvp[20] = vr[8];
  }
  __syncthreads();

  if (active) {
    const float* kvb = &sKV[il][0][0];
    float s[NQ];
    float m = -3.4e38f;
#pragma unroll
    for (int j = 0; j < NQ; ++j) {
      float sc = dot9(kvb + j * KVROW, q) * (1.0f / 3.0f) + sMask[j];
      s[j] = sc;
      m = fmaxf(m, sc);
    }
    float sum = 0.f;
#pragma unroll
    for (int j = 0; j < NQ; ++j) {
      float p = __expf(s[j] - m);
      s[j] = p;
      sum += p;
    }
    const float inv = 1.0f / sum;

    float o[KVD];
#pragma unroll
    for (int d = 0; d < KVD; ++d) o[d] = 0.f;
#pragma unroll
    for (int j = 0; j < NQ; ++j) {
      const float* vp = kvb + j * KVROW + 12;
      float4 a = *(const float4*)(vp);
      float4 b = *(const float4*)(vp + 4);
      float c = vp[8];
      const float p = s[j];
      o[0] = fmaf(p, a.x, o[0]);
      o[1] = fmaf(p, a.y, o[1]);
      o[2] = fmaf(p, a.z, o[2]);
      o[3] = fmaf(p, a.w, o[3]);
      o[4] = fmaf(p, b.x, o[4]);
      o[5] = fmaf(p, b.y, o[5]);
      o[6] = fmaf(p, b.z, o[6]);
      o[7] = fmaf(p, b.w, o[7]);
      o[8] = fmaf(p, c,   o[8]);
    }

    float r[KVD];
    float mu = 0.f;
#pragma unroll
    for (int d = 0; d < KVD; ++d) { r[d] = fmaf(o[d], inv, xv[d]); mu += r[d]; }
    mu *= (1.0f / 9.0f);
    float var = 0.f;
#pragma unroll
    for (int d = 0; d < KVD; ++d) { float t = r[d] - mu; var = fmaf(t, t, var); }
    var *= (1.0f / 9.0f);
    const float rs = rsqrtf(var + 1e-5f);
    float* op = out + item * 225 + tk * KVD;
#pragma unroll
    for (int d = 0; d < KVD; ++d)
      op[d] = fmaf((r[d] - mu) * rs, sG[d], sBeta[d]);
  }
}

extern "C" void kernel_launch(void* const* d_in, const int* in_sizes, int n_in,
                              void* d_out, int out_size, void* d_ws, size_t ws_size,
                              hipStream_t stream) {
  const float* x     = (const float*)d_in[0];
  const float* mask  = (const float*)d_in[1];
  const float* Wq    = (const float*)d_in[2];
  const float* bq    = (const float*)d_in[3];
  const float* Wk    = (const float*)d_in[4];
  const float* bk    = (const float*)d_in[5];
  const float* Wv    = (const float*)d_in[6];
  const float* bv    = (const float*)d_in[7];
  const float* gamma = (const float*)d_in[8];
  const float* beta  = (const float*)d_in[9];
  float* out = (float*)d_out;
  const int B = in_sizes[0] / 225;
  const int grid = (B + ITEMS_PER_BLOCK - 1) / ITEMS_PER_BLOCK;
  attn_fused<<<grid, NTHREADS, 0, stream>>>(x, mask, Wq, bq, Wk, bk, Wv, bv,
                                            gamma, beta, out, B);
}